// Round 3
// baseline (2575.689 us; speedup 1.0000x reference)
//
#include <hip/hip_runtime.h>

#define NCH 120

// ---------------------------------------------------------------------------
// Prep kernel: binarize conv_w into 120x(4xu32) COMPLEMENTED sign masks
// (nw = ~sign_mask, so XNOR(sx,w) == sx^nw -> saves a NOT per word) plus
// nonzero masks, and per-channel coefficients {conv_b-128, gn_w, gn_b, lin_w}.
// ws layout (u32 units): [0,480) ~sign, [480,960) nz, [960,1440) coef(float),
// [1440] any_w_zero flag.
// ---------------------------------------------------------------------------
__global__ void prep_kernel(const float* __restrict__ conv_w,
                            const float* __restrict__ conv_b,
                            const float* __restrict__ gn_w,
                            const float* __restrict__ gn_b,
                            const float* __restrict__ lin_w,
                            unsigned* __restrict__ ws)
{
    __shared__ unsigned s_any;
    if (threadIdx.x == 0) s_any = 0u;
    __syncthreads();
    int c = threadIdx.x;
    if (c < NCH) {
        unsigned sw[4] = {0u,0u,0u,0u};
        unsigned nz[4] = {0u,0u,0u,0u};
        const float* wr = conv_w + c * NCH;
        for (int k = 0; k < NCH; ++k) {
            float w = wr[k];
            unsigned wd = (unsigned)k >> 5, bit = (unsigned)k & 31u;
            sw[wd] |= (w > 0.0f ? 1u : 0u) << bit;
            nz[wd] |= (w != 0.0f ? 1u : 0u) << bit;
        }
        bool anyz = !(nz[0] == 0xFFFFFFFFu && nz[1] == 0xFFFFFFFFu &&
                      nz[2] == 0xFFFFFFFFu && nz[3] == 0x00FFFFFFu);
        if (anyz) atomicOr(&s_any, 1u);
        for (int w = 0; w < 4; ++w) {
            ws[c * 4 + w]       = ~sw[w];        // complemented
            ws[480 + c * 4 + w] = nz[w];
        }
        float* cf = (float*)(ws + 960);
        cf[c * 4 + 0] = conv_b[c] - 128.0f;  // folded Y-offset
        cf[c * 4 + 1] = gn_w[c];
        cf[c * 4 + 2] = gn_b[c];
        cf[c * 4 + 3] = lin_w[c];
    }
    __syncthreads();
    if (threadIdx.x == 0) ws[1440] = s_any;
}

// ---------------------------------------------------------------------------
// Slow path for one sample (exact sign(0) handling: x==0.5 or w==0). Rare.
// sh_nw holds COMPLEMENTED sign masks: match-popcount = popc((sx^nw)&m).
// ---------------------------------------------------------------------------
__device__ __forceinline__ float slow_sample(const float* __restrict__ xr,
                                             const unsigned* sxa,
                                             const uint4* sh_nw,
                                             const uint4* sh_nz,
                                             const float4* sh_coef)
{
    unsigned nxa[4] = {0u,0u,0u,0u};
    for (int j = 0; j < 30; ++j) {
        float4 v = *(const float4*)(xr + 4 * j);
        unsigned u0 = __float_as_uint(0.5f - v.x);
        unsigned u1 = __float_as_uint(0.5f - v.y);
        unsigned u2 = __float_as_uint(0.5f - v.z);
        unsigned u3 = __float_as_uint(0.5f - v.w);
        const int w = j >> 3;
        const int p = (j & 7) * 4;
        nxa[w] |= (u0 != 0u ? 1u : 0u) << (p + 0);
        nxa[w] |= (u1 != 0u ? 1u : 0u) << (p + 1);
        nxa[w] |= (u2 != 0u ? 1u : 0u) << (p + 2);
        nxa[w] |= (u3 != 0u ? 1u : 0u) << (p + 3);
    }
    unsigned sumY = 0u, sumYY = 0u;
    for (int c = 0; c < NCH; ++c) {
        uint4 w = sh_nw[c];
        uint4 z = sh_nz[c];
        unsigned m0 = nxa[0] & z.x, m1 = nxa[1] & z.y;
        unsigned m2 = nxa[2] & z.z, m3 = nxa[3] & z.w;
        unsigned p = __popc((sxa[0] ^ w.x) & m0)
                   + __popc((sxa[1] ^ w.y) & m1)
                   + __popc((sxa[2] ^ w.z) & m2)
                   + __popc((sxa[3] ^ w.w) & m3);
        unsigned cnt = __popc(m0) + __popc(m1) + __popc(m2) + __popc(m3);
        int Y = 2 * (int)p - (int)cnt + 128;
        sumY  += (unsigned)Y;
        sumYY += (unsigned)(Y * Y);
    }
    float meanY = (float)sumY * (1.0f / 120.0f);
    float varY  = (float)sumYY * (1.0f / 120.0f) - meanY * meanY;
    float rstd  = __builtin_amdgcn_rsqf(varY + 1e-5f);
    float nb    = -(meanY - 128.0f) * rstd;
    float acc = 0.0f;
    for (int c = 0; c < NCH; ++c) {
        uint4 w = sh_nw[c];
        uint4 z = sh_nz[c];
        unsigned m0 = nxa[0] & z.x, m1 = nxa[1] & z.y;
        unsigned m2 = nxa[2] & z.z, m3 = nxa[3] & z.w;
        unsigned p = __popc((sxa[0] ^ w.x) & m0)
                   + __popc((sxa[1] ^ w.y) & m1)
                   + __popc((sxa[2] ^ w.z) & m2)
                   + __popc((sxa[3] ^ w.w) & m3);
        unsigned cnt = __popc(m0) + __popc(m1) + __popc(m2) + __popc(m3);
        int Y = 2 * (int)p - (int)cnt + 128;
        float4 cf = sh_coef[c];
        float yf = (float)Y + cf.x;
        float n  = fmaf(yf, rstd, nb);
        float g  = fmaf(n, cf.y, cf.z);
        float s  = g * __builtin_amdgcn_rcpf(1.0f + fabsf(g));
        acc = fmaf(s, cf.w, acc);
    }
    return acc;
}

// ---------------------------------------------------------------------------
// Main kernel, v3: 2 samples per thread.
//  - Each wave owns 128 consecutive samples = 15360 consecutive floats.
//    Staging: 240 coalesced 4B/lane loads; __ballot(x>0.5) -> u64 per iter;
//    lane 0 stores to the wave's private LDS ballot region.
//  - Each thread assembles TWO 120-bit masks (samples lane and lane+64) and
//    runs the XNOR-popcount fast path for both, SHARING one sh_nw[c] and one
//    sh_coef[c] LDS read per channel between the two samples (halves the
//    LDS-pipe traffic per sample, which was the R2 co-bottleneck).
//  - Y_c = 2*popc128(sx ^ nw_c) - 8 (pads of sx zero, nw pads one).
//  - Exact integer stats, fp32 norm+affine+softsign+dot epilogue.
// ---------------------------------------------------------------------------
__global__ __launch_bounds__(256, 4) void bnn_kernel(
    const float* __restrict__ x,
    const unsigned* __restrict__ ws,
    float* __restrict__ out,
    int B)
{
    __shared__ uint4  sh_nw[NCH];
    __shared__ uint4  sh_nz[NCH];
    __shared__ float4 sh_coef[NCH];
    __shared__ unsigned long long s_bal[4][242];   // 240 ballots + pad
    __shared__ unsigned sh_flag;

    const int tid  = threadIdx.x;
    const int lane = tid & 63;
    const int wv   = tid >> 6;

    if (tid < NCH) {
        sh_nw[tid]   = ((const uint4*)ws)[tid];
        sh_nz[tid]   = ((const uint4*)ws)[120 + tid];
        sh_coef[tid] = ((const float4*)ws)[240 + tid];
    }
    if (tid == 0) sh_flag = ws[1440];

    // ---- staging: 128 samples per wave, coalesced loads + ballot packing ----
    const long long wsample0 = (long long)blockIdx.x * 512 + wv * 128;
    const float* __restrict__ wx = x + wsample0 * NCH;
    unsigned minu = 0xFFFFFFFFu;
    const bool fullwave = (wsample0 + 128 <= (long long)B);
    if (fullwave) {
#pragma unroll
        for (int jb = 0; jb < 24; ++jb) {
            float v[10];
#pragma unroll
            for (int k = 0; k < 10; ++k)
                v[k] = wx[(jb * 10 + k) * 64 + lane];
#pragma unroll
            for (int k = 0; k < 10; ++k) {
                unsigned u = __float_as_uint(0.5f - v[k]);
                minu = min(minu, u);
                unsigned long long b = __ballot(v[k] > 0.5f);
                if (lane == 0) s_bal[wv][jb * 10 + k] = b;
            }
        }
    } else {
        const long long lim = (long long)B * NCH - wsample0 * NCH;
        for (int it = 0; it < 240; ++it) {
            long long idx = (long long)it * 64 + lane;
            float vv = (idx < lim) ? wx[idx] : 0.0f;
            unsigned u = __float_as_uint(0.5f - vv);
            minu = min(minu, u);
            unsigned long long b = __ballot(vv > 0.5f);
            if (lane == 0) s_bal[wv][it] = b;
        }
    }
    const bool wave_slow = __any(minu == 0u);
    __syncthreads();

    const long long sA = wsample0 + lane;
    const long long sB = sA + 64;

    // ---- assemble 120-bit masks for both samples ----
    const unsigned* wr = (const unsigned*)&s_bal[wv][0];
    unsigned sxaA[4], sxaB[4];
    {
        const unsigned bp = (unsigned)lane * 120u;
        const unsigned wi = bp >> 5, sh = bp & 31u;
        unsigned t0 = wr[wi], t1 = wr[wi+1], t2 = wr[wi+2], t3 = wr[wi+3], t4 = wr[wi+4];
        sxaA[0] = (unsigned)((((unsigned long long)t1 << 32) | t0) >> sh);
        sxaA[1] = (unsigned)((((unsigned long long)t2 << 32) | t1) >> sh);
        sxaA[2] = (unsigned)((((unsigned long long)t3 << 32) | t2) >> sh);
        sxaA[3] = (unsigned)((((unsigned long long)t4 << 32) | t3) >> sh) & 0x00FFFFFFu;
    }
    {
        const unsigned bp = (unsigned)(lane + 64) * 120u;
        const unsigned wi = bp >> 5, sh = bp & 31u;
        unsigned t0 = wr[wi], t1 = wr[wi+1], t2 = wr[wi+2], t3 = wr[wi+3], t4 = wr[wi+4];
        sxaB[0] = (unsigned)((((unsigned long long)t1 << 32) | t0) >> sh);
        sxaB[1] = (unsigned)((((unsigned long long)t2 << 32) | t1) >> sh);
        sxaB[2] = (unsigned)((((unsigned long long)t3 << 32) | t2) >> sh);
        sxaB[3] = (unsigned)((((unsigned long long)t4 << 32) | t3) >> sh) & 0x00FFFFFFu;
    }

    const bool fast = !wave_slow && (sh_flag == 0u);

    if (fast) {
        unsigned ywA[30], ywB[30];
        unsigned sumYA = 0u, sumYYA = 0u, sumYB = 0u, sumYYB = 0u;
#pragma unroll
        for (int c = 0; c < NCH; ++c) {
            uint4 w = sh_nw[c];                     // one read, two samples
            unsigned pA = __popc(sxaA[0] ^ w.x);
            pA = __popc(sxaA[1] ^ w.y) + pA;
            pA = __popc(sxaA[2] ^ w.z) + pA;
            pA = __popc(sxaA[3] ^ w.w) + pA;
            unsigned pB = __popc(sxaB[0] ^ w.x);
            pB = __popc(sxaB[1] ^ w.y) + pB;
            pB = __popc(sxaB[2] ^ w.z) + pB;
            pB = __popc(sxaB[3] ^ w.w) + pB;
            unsigned YA = 2u * pA - 8u;             // y + 128, in [8,248]
            unsigned YB = 2u * pB - 8u;
            if ((c & 3) == 0) { ywA[c >> 2] = YA;               ywB[c >> 2] = YB; }
            else              { ywA[c >> 2] |= YA << ((c & 3) * 8); ywB[c >> 2] |= YB << ((c & 3) * 8); }
            sumYA += YA;  sumYYA += __umul24(YA, YA);
            sumYB += YB;  sumYYB += __umul24(YB, YB);
        }
        float meanA = (float)sumYA * (1.0f / 120.0f);
        float varA  = (float)sumYYA * (1.0f / 120.0f) - meanA * meanA;
        float rstdA = __builtin_amdgcn_rsqf(varA + 1e-5f);
        float nbA   = -(meanA - 128.0f) * rstdA;
        float meanB = (float)sumYB * (1.0f / 120.0f);
        float varB  = (float)sumYYB * (1.0f / 120.0f) - meanB * meanB;
        float rstdB = __builtin_amdgcn_rsqf(varB + 1e-5f);
        float nbB   = -(meanB - 128.0f) * rstdB;
        float accA = 0.0f, accB = 0.0f;
#pragma unroll
        for (int c = 0; c < NCH; ++c) {
            float4 cf = sh_coef[c];                 // one read, two samples
            unsigned YA = (ywA[c >> 2] >> ((c & 3) * 8)) & 0xFFu;
            unsigned YB = (ywB[c >> 2] >> ((c & 3) * 8)) & 0xFFu;
            float yfA = (float)YA + cf.x;
            float yfB = (float)YB + cf.x;
            float nA  = fmaf(yfA, rstdA, nbA);
            float nB  = fmaf(yfB, rstdB, nbB);
            float gA  = fmaf(nA, cf.y, cf.z);
            float gB  = fmaf(nB, cf.y, cf.z);
            float sA_ = gA * __builtin_amdgcn_rcpf(1.0f + fabsf(gA));
            float sB_ = gB * __builtin_amdgcn_rcpf(1.0f + fabsf(gB));
            accA = fmaf(sA_, cf.w, accA);
            accB = fmaf(sB_, cf.w, accB);
        }
        if (sA < B) out[sA] = accA;
        if (sB < B) out[sB] = accB;
    } else {
        if (sA < B) out[sA] = slow_sample(x + sA * NCH, sxaA, sh_nw, sh_nz, sh_coef);
        if (sB < B) out[sB] = slow_sample(x + sB * NCH, sxaB, sh_nw, sh_nz, sh_coef);
    }
}

extern "C" void kernel_launch(void* const* d_in, const int* in_sizes, int n_in,
                              void* d_out, int out_size, void* d_ws, size_t ws_size,
                              hipStream_t stream) {
    const float* x      = (const float*)d_in[0];
    const float* conv_w = (const float*)d_in[1];
    const float* conv_b = (const float*)d_in[2];
    const float* gn_w   = (const float*)d_in[3];
    const float* gn_b   = (const float*)d_in[4];
    const float* lin_w  = (const float*)d_in[5];
    unsigned* ws = (unsigned*)d_ws;
    float* out = (float*)d_out;

    const int B = in_sizes[0] / NCH;
    prep_kernel<<<1, 128, 0, stream>>>(conv_w, conv_b, gn_w, gn_b, lin_w, ws);
    const int grid = (B + 511) / 512;
    bnn_kernel<<<grid, 256, 0, stream>>>(x, ws, out, B);
}

// Round 4
// 151.878 us; speedup vs baseline: 16.9590x; 16.9590x over previous
//
#include <hip/hip_runtime.h>

#define NCH 120

// ---------------------------------------------------------------------------
// Prep kernel: binarize conv_w into 120x(4xu32) COMPLEMENTED sign masks
// (nw = ~sign_mask, so XNOR(sx,w) == sx^nw) plus nonzero masks, and
// per-channel coefficients {conv_b-128, gn_w, gn_b, lin_w}.
// ws layout (u32 units): [0,480) ~sign, [480,960) nz, [960,1440) coef(float),
// [1440] any_w_zero flag.
// ---------------------------------------------------------------------------
__global__ void prep_kernel(const float* __restrict__ conv_w,
                            const float* __restrict__ conv_b,
                            const float* __restrict__ gn_w,
                            const float* __restrict__ gn_b,
                            const float* __restrict__ lin_w,
                            unsigned* __restrict__ ws)
{
    __shared__ unsigned s_any;
    if (threadIdx.x == 0) s_any = 0u;
    __syncthreads();
    int c = threadIdx.x;
    if (c < NCH) {
        unsigned sw[4] = {0u,0u,0u,0u};
        unsigned nz[4] = {0u,0u,0u,0u};
        const float* wr = conv_w + c * NCH;
        for (int k = 0; k < NCH; ++k) {
            float w = wr[k];
            unsigned wd = (unsigned)k >> 5, bit = (unsigned)k & 31u;
            sw[wd] |= (w > 0.0f ? 1u : 0u) << bit;
            nz[wd] |= (w != 0.0f ? 1u : 0u) << bit;
        }
        bool anyz = !(nz[0] == 0xFFFFFFFFu && nz[1] == 0xFFFFFFFFu &&
                      nz[2] == 0xFFFFFFFFu && nz[3] == 0x00FFFFFFu);
        if (anyz) atomicOr(&s_any, 1u);
        for (int w = 0; w < 4; ++w) {
            ws[c * 4 + w]       = ~sw[w];        // complemented sign mask
            ws[480 + c * 4 + w] = nz[w];
        }
        float* cf = (float*)(ws + 960);
        cf[c * 4 + 0] = conv_b[c] - 128.0f;  // folded Y-offset
        cf[c * 4 + 1] = gn_w[c];
        cf[c * 4 + 2] = gn_b[c];
        cf[c * 4 + 3] = lin_w[c];
    }
    __syncthreads();
    if (threadIdx.x == 0) ws[1440] = s_any;
}

// ---------------------------------------------------------------------------
// Slow path for one sample (exact sign(0): x==0.5 or w==0). Ultra-rare.
// Reads weights via wave-uniform global (scalar cache).
// ---------------------------------------------------------------------------
__device__ float slow_sample(const float* __restrict__ xr,
                             const unsigned* sxa,
                             const unsigned* __restrict__ ws)
{
    const uint4*  nwp = (const uint4*)ws;
    const uint4*  nzp = (const uint4*)(ws + 480);
    const float4* cfp = (const float4*)(ws + 960);
    unsigned nxa[4] = {0u,0u,0u,0u};
    for (int j = 0; j < 30; ++j) {
        float4 v = *(const float4*)(xr + 4 * j);
        unsigned u0 = __float_as_uint(0.5f - v.x);
        unsigned u1 = __float_as_uint(0.5f - v.y);
        unsigned u2 = __float_as_uint(0.5f - v.z);
        unsigned u3 = __float_as_uint(0.5f - v.w);
        const int w = j >> 3;
        const int p = (j & 7) * 4;
        nxa[w] |= (u0 != 0u ? 1u : 0u) << (p + 0);
        nxa[w] |= (u1 != 0u ? 1u : 0u) << (p + 1);
        nxa[w] |= (u2 != 0u ? 1u : 0u) << (p + 2);
        nxa[w] |= (u3 != 0u ? 1u : 0u) << (p + 3);
    }
    unsigned sumY = 0u, sumYY = 0u;
    for (int c = 0; c < NCH; ++c) {
        uint4 w = nwp[c];
        uint4 z = nzp[c];
        unsigned m0 = nxa[0] & z.x, m1 = nxa[1] & z.y;
        unsigned m2 = nxa[2] & z.z, m3 = nxa[3] & z.w;
        unsigned p = __popc((sxa[0] ^ w.x) & m0)
                   + __popc((sxa[1] ^ w.y) & m1)
                   + __popc((sxa[2] ^ w.z) & m2)
                   + __popc((sxa[3] ^ w.w) & m3);
        unsigned cnt = __popc(m0) + __popc(m1) + __popc(m2) + __popc(m3);
        int Y = 2 * (int)p - (int)cnt + 128;
        sumY  += (unsigned)Y;
        sumYY += (unsigned)(Y * Y);
    }
    float meanY = (float)sumY * (1.0f / 120.0f);
    float varY  = (float)sumYY * (1.0f / 120.0f) - meanY * meanY;
    float rstd  = __builtin_amdgcn_rsqf(varY + 1e-5f);
    float nb    = -(meanY - 128.0f) * rstd;
    float acc = 0.0f;
    for (int c = 0; c < NCH; ++c) {
        uint4 w = nwp[c];
        uint4 z = nzp[c];
        unsigned m0 = nxa[0] & z.x, m1 = nxa[1] & z.y;
        unsigned m2 = nxa[2] & z.z, m3 = nxa[3] & z.w;
        unsigned p = __popc((sxa[0] ^ w.x) & m0)
                   + __popc((sxa[1] ^ w.y) & m1)
                   + __popc((sxa[2] ^ w.z) & m2)
                   + __popc((sxa[3] ^ w.w) & m3);
        unsigned cnt = __popc(m0) + __popc(m1) + __popc(m2) + __popc(m3);
        int Y = 2 * (int)p - (int)cnt + 128;
        float4 cf = cfp[c];
        float yf = (float)Y + cf.x;
        float n  = fmaf(yf, rstd, nb);
        float g  = fmaf(n, cf.y, cf.z);
        float s  = g * __builtin_amdgcn_rcpf(1.0f + fabsf(g));
        acc = fmaf(s, cf.w, acc);
    }
    return acc;
}

// ---------------------------------------------------------------------------
// Main kernel, v4: 1 sample/thread (R2 structure) + SCALAR-CACHE weights.
//  - Ballot transpose (coalesced 4B/lane loads -> __ballot -> LDS) unchanged.
//  - Weight masks / coefficients are wave-uniform: read from global with
//    compile-time indices -> s_load_dwordx4 via the scalar cache. Zero LDS
//    traffic in the popcount loop (R2's LDS pipe was ~90% busy; this moves
//    that entire load onto the idle scalar pipe).
//  - LDS footprint ~3.9 KB (ballot region only); no launch_bounds min-waves
//    constraint (R3's spill disaster: 60 VGPRs of yw under a 128-VGPR cap).
// ---------------------------------------------------------------------------
__global__ __launch_bounds__(256) void bnn_kernel(
    const float* __restrict__ x,
    const unsigned* __restrict__ ws,
    float* __restrict__ out,
    int B)
{
    __shared__ unsigned long long s_bal[4][121];   // 120 ballots + 1 pad/wave

    const int tid  = threadIdx.x;
    const int lane = tid & 63;
    const int wv   = tid >> 6;

    const uint4*  nwp = (const uint4*)ws;          // ~sign masks (uniform idx)
    const float4* cfp = (const float4*)(ws + 960); // coefficients

    // ---- staging: 64 samples per wave, coalesced loads + ballot packing ----
    const long long wsample0 = (long long)blockIdx.x * 256 + wv * 64;
    const float* __restrict__ wx = x + wsample0 * NCH;
    unsigned minu = 0xFFFFFFFFu;
    const bool fullwave = (wsample0 + 64 <= (long long)B);
    if (fullwave) {
#pragma unroll
        for (int j = 0; j < 8; ++j) {
            float v[15];
#pragma unroll
            for (int k = 0; k < 15; ++k)
                v[k] = wx[(j * 15 + k) * 64 + lane];
#pragma unroll
            for (int k = 0; k < 15; ++k) {
                unsigned u = __float_as_uint(0.5f - v[k]);
                minu = min(minu, u);
                unsigned long long b = __ballot(v[k] > 0.5f);
                if (lane == 0) s_bal[wv][j * 15 + k] = b;
            }
        }
    } else {
        const long long lim = (long long)B * NCH - wsample0 * NCH;
        for (int it = 0; it < 120; ++it) {
            long long idx = (long long)it * 64 + lane;
            float vv = (idx < lim) ? wx[idx] : 0.0f;
            unsigned u = __float_as_uint(0.5f - vv);
            minu = min(minu, u);
            unsigned long long b = __ballot(vv > 0.5f);
            if (lane == 0) s_bal[wv][it] = b;
        }
    }
    const bool wave_slow = __any(minu == 0u);
    __syncthreads();

    const long long bi = wsample0 + lane;
    if (bi >= B) return;

    // ---- assemble this sample's 120-bit mask from the wave's bit region ----
    const unsigned bitpos = (unsigned)lane * 120u;
    const unsigned widx   = bitpos >> 5;
    const unsigned sh     = bitpos & 31u;
    const unsigned* wr = (const unsigned*)&s_bal[wv][0];
    unsigned t0 = wr[widx], t1 = wr[widx + 1], t2 = wr[widx + 2],
             t3 = wr[widx + 3], t4 = wr[widx + 4];
    unsigned sxa[4];
    sxa[0] = (unsigned)((((unsigned long long)t1 << 32) | t0) >> sh);
    sxa[1] = (unsigned)((((unsigned long long)t2 << 32) | t1) >> sh);
    sxa[2] = (unsigned)((((unsigned long long)t3 << 32) | t2) >> sh);
    sxa[3] = (unsigned)((((unsigned long long)t4 << 32) | t3) >> sh) & 0x00FFFFFFu;

    const bool fast = !wave_slow && (ws[1440] == 0u);

    if (fast) {
        unsigned yw[30];
        unsigned sumY = 0u, sumYY = 0u;
#pragma unroll
        for (int c = 0; c < NCH; ++c) {
            uint4 w = nwp[c];                      // s_load (scalar cache)
            unsigned p = __popc(sxa[0] ^ w.x);
            p = __popc(sxa[1] ^ w.y) + p;
            p = __popc(sxa[2] ^ w.z) + p;
            p = __popc(sxa[3] ^ w.w) + p;
            unsigned Y = 2u * p - 8u;              // = y_c + 128, in [8,248]
            if ((c & 3) == 0) yw[c >> 2] = Y;
            else              yw[c >> 2] |= Y << ((c & 3) * 8);
            sumY  += Y;
            sumYY += __umul24(Y, Y);
        }
        float meanY = (float)sumY * (1.0f / 120.0f);
        float varY  = (float)sumYY * (1.0f / 120.0f) - meanY * meanY;
        float rstd  = __builtin_amdgcn_rsqf(varY + 1e-5f);
        float nb    = -(meanY - 128.0f) * rstd;
        float acc = 0.0f;
#pragma unroll
        for (int c = 0; c < NCH; ++c) {
            float4 cf = cfp[c];                    // s_load (scalar cache)
            unsigned Y = (yw[c >> 2] >> ((c & 3) * 8)) & 0xFFu;
            float yf = (float)Y + cf.x;            // y_c + conv_b
            float n  = fmaf(yf, rstd, nb);         // groupnorm core
            float g  = fmaf(n, cf.y, cf.z);        // * gn_w + gn_b
            float s  = g * __builtin_amdgcn_rcpf(1.0f + fabsf(g));  // softsign
            acc = fmaf(s, cf.w, acc);              // dot lin_w
        }
        out[bi] = acc;
    } else {
        out[bi] = slow_sample(x + bi * NCH, sxa, ws);
    }
}

extern "C" void kernel_launch(void* const* d_in, const int* in_sizes, int n_in,
                              void* d_out, int out_size, void* d_ws, size_t ws_size,
                              hipStream_t stream) {
    const float* x      = (const float*)d_in[0];
    const float* conv_w = (const float*)d_in[1];
    const float* conv_b = (const float*)d_in[2];
    const float* gn_w   = (const float*)d_in[3];
    const float* gn_b   = (const float*)d_in[4];
    const float* lin_w  = (const float*)d_in[5];
    unsigned* ws = (unsigned*)d_ws;
    float* out = (float*)d_out;

    const int B = in_sizes[0] / NCH;
    prep_kernel<<<1, 128, 0, stream>>>(conv_w, conv_b, gn_w, gn_b, lin_w, ws);
    const int grid = (B + 255) / 256;
    bnn_kernel<<<grid, 256, 0, stream>>>(x, ws, out, B);
}